// Round 13
// baseline (597.030 us; speedup 1.0000x reference)
//
#include <hip/hip_runtime.h>
#include <hip/hip_bf16.h>
#include <hip/hip_fp8.h>

#define NU_ 100000
#define NT_ 200000
#define NE_ 1000000
#define HD  64
#define NL  3

// dinv region offsets (node-keyed)
#define OFF0 0                   // u2u dst (NU)  [selfloop]
#define OFF1 (NU_)               // t2t dst (NT)  [selfloop]
#define OFF4 (2 * NU_ + 2 * NT_) // u2t src (NU)
#define OFF5 (3 * NU_ + 2 * NT_) // t2u src (NT)
#define HTOT (3 * NU_ + 3 * NT_) // 900k
#define RPT2 (NU_ + NT_)         // merged node count (300k)

// bucket partition (no-far-atomic CSR build)
#define PB1  512
#define BKP  2048
#define NBKC 147
#define NBKS 147
#define NBKT (NBKC + NBKS)

// packed-weight layout (f16 fragments, 512 f16 per fragment)
#define WPK_EMBU 0
#define WPK_EMBT 2048
#define WPK_CONV 6144      // 12 mats x 8 frags x 512
#define WPK_G0U  55296     // composed layer-0 user: 2 mats x 4 frags x 512
#define WPK_G0T  59392     // composed layer-0 txn: 2 mats x 8 frags x 512
#define WPK_TOT  67584
#define PK_ELEMS (WPK_TOT + 256)
#define PKB      ((PK_ELEMS + 255) / 256)   // 265
#define CVB      237                         // ceil(60417/256)

// grids
#define GMU 512
#define GMT 1024
#define GBU 3125           // NU/32 gather blocks (32 dsts per block)
#define GBT 6250           // NT/32

typedef float floatx2 __attribute__((ext_vector_type(2)));
typedef _Float16 f16x8 __attribute__((ext_vector_type(8)));
typedef float f32x4 __attribute__((ext_vector_type(4)));
typedef unsigned short u16x8 __attribute__((ext_vector_type(8)));
typedef int i32x4 __attribute__((ext_vector_type(4)));

// ---------------- fp8 helpers ----------------
__device__ __forceinline__ unsigned char enc_fp8(float v) {
    return (unsigned char)__hip_cvt_float_to_fp8(v, __HIP_SATFINITE, __HIP_E4M3);
}

__device__ __forceinline__ float dec1_fp8(unsigned int u) {
    int e = (u >> 3) & 15;
    int m = u & 7;
    int mant = m | (e ? 8 : 0);
    if (u & 0x80) mant = -mant;
    int ex = (e ? e : 1) - 10;
    return (float)mant * __uint_as_float((unsigned int)(ex + 127) << 23);
}

__device__ __forceinline__ void dec4_fp8(unsigned int u, float* f) {
#if __has_builtin(__builtin_amdgcn_cvt_pk_f32_fp8)
    floatx2 lo = __builtin_amdgcn_cvt_pk_f32_fp8((int)u, false);
    floatx2 hi = __builtin_amdgcn_cvt_pk_f32_fp8((int)u, true);
    f[0] = lo.x; f[1] = lo.y; f[2] = hi.x; f[3] = hi.y;
#else
    f[0] = dec1_fp8(u & 0xff);
    f[1] = dec1_fp8((u >> 8) & 0xff);
    f[2] = dec1_fp8((u >> 16) & 0xff);
    f[3] = dec1_fp8((u >> 24) & 0xff);
#endif
}

// ---------------- dtype detection + aux zeroing ----------------
__global__ void detect_dtype(const unsigned short* __restrict__ x, int* __restrict__ flag,
                             float* __restrict__ gsum, int* __restrict__ gcnt,
                             int* __restrict__ done, int n) {
    __shared__ int s_big;
    if (threadIdx.x == 0) s_big = 0;
    __syncthreads();
    int big = 0;
    for (int i = threadIdx.x; i < n; i += blockDim.x) {
        float v = __uint_as_float(((unsigned int)x[i]) << 16);
        if (!(fabsf(v) < 1.0e4f)) big = 1;
    }
    if (big) atomicAdd(&s_big, 1);
    if (threadIdx.x < 64) gsum[threadIdx.x] = 0.f;
    for (int j = threadIdx.x; j < NBKT; j += 256) gcnt[j] = 0;
    if (threadIdx.x == 0) *done = 0;
    __syncthreads();
    if (threadIdx.x == 0) flag[0] = (s_big > 0) ? 0 : 1;
}

// ---------------- weight conversion (device body) ----------------
struct Ptr10 { const void* p[10]; };

__device__ __forceinline__ void cvt_dev(int i, Ptr10 src, float* __restrict__ dst,
                                        const int* __restrict__ flag) {
    const int c[11] = {0, 2048, 2112, 6208, 6272, 55424, 56192, 60288, 60352, 60416, 60417};
    if (i >= 60417) return;
    int r = 0;
#pragma unroll
    for (int k = 1; k < 10; ++k)
        if (i >= c[k]) r = k;
    int e = i - c[r];
    if (flag[0]) {
        unsigned short u = ((const unsigned short*)src.p[r])[e];
        dst[i] = __uint_as_float(((unsigned int)u) << 16);
    } else {
        dst[i] = ((const float*)src.p[r])[e];
    }
}

// ---------------- pack weights + compose layer-0 (We@Wc, be@Wc) ----------------
__device__ __forceinline__ void pack_dev(int gid, const float* __restrict__ wts,
                                         _Float16* __restrict__ wpk,
                                         float* __restrict__ bcomp) {
    if (gid >= PK_ELEMS) return;
    if (gid < WPK_G0U) {
        const float* W;
        int r, KS;
        if (gid < WPK_EMBT) { W = wts; r = gid; KS = 1; }
        else if (gid < WPK_CONV) { W = wts + 2112; r = gid - WPK_EMBT; KS = 2; }
        else {
            int mat = (gid - WPK_CONV) >> 12;
            W = wts + 6272 + mat * 4096;
            r = (gid - WPK_CONV) & 4095;
            KS = 2;
        }
        int j = r & 7;
        int lane = (r >> 3) & 63;
        int f = r >> 9;
        int ct = f / KS;
        int s = f - ct * KS;
        int k = 32 * s + 8 * (lane >> 4) + j;
        int n = 16 * ct + (lane & 15);
        wpk[gid] = (_Float16)W[k * 64 + n];
    } else if (gid < WPK_TOT) {
        const float* We;
        int matc, rr, KS;
        if (gid < WPK_G0T) {
            int r = gid - WPK_G0U;
            matc = (r >> 11) ? 2 : 0;
            rr = r & 2047;
            We = wts;
            KS = 1;
        } else {
            int r = gid - WPK_G0T;
            matc = (r >> 12) ? 3 : 1;
            rr = r & 4095;
            We = wts + 2112;
            KS = 2;
        }
        const float* Wc = wts + 6272 + matc * 4096;
        int j = rr & 7;
        int lane = (rr >> 3) & 63;
        int f = rr >> 9;
        int ct = f / KS;
        int s = f - ct * KS;
        int k = 32 * s + 8 * (lane >> 4) + j;
        int n = 16 * ct + (lane & 15);
        float acc = 0.f;
#pragma unroll
        for (int q = 0; q < 64; ++q)
            acc = fmaf(We[k * 64 + q], Wc[q * 64 + n], acc);
        wpk[gid] = (_Float16)acc;
    } else {
        int q = gid - WPK_TOT;
        int mat = q >> 6;
        int n = q & 63;
        const float* be = (mat == 0 || mat == 2) ? (wts + 2048) : (wts + 6208);
        const float* Wc = wts + 6272 + mat * 4096;
        float acc = 0.f;
#pragma unroll
        for (int k = 0; k < 64; ++k)
            acc = fmaf(be[k], Wc[k * 64 + n], acc);
        bcomp[q] = acc;
    }
}

// ---------------- partition pass 1: per-block bucket counts (LDS) ----------------
__device__ __forceinline__ void p1_dev(int bid, const int* __restrict__ eu2u,
                                       const int* __restrict__ et2t,
                                       const int* __restrict__ eu2t,
                                       const int* __restrict__ et2u,
                                       int* __restrict__ gcnt, int* __restrict__ bofs) {
    __shared__ int cnt[NBKT];
    for (int j = threadIdx.x; j < NBKT; j += 256) cnt[j] = 0;
    __syncthreads();
    for (int i = bid * 256 + threadIdx.x; i < 6 * NE_; i += PB1 * 256) {
        int b;
        if (i < 4 * NE_) {
            int m;
            if (i < NE_)          m = __builtin_nontemporal_load(eu2u + i + NE_);
            else if (i < 2 * NE_) m = NU_ + __builtin_nontemporal_load(et2t + i);
            else if (i < 3 * NE_) m = NU_ + __builtin_nontemporal_load(eu2t + i - NE_);
            else                  m = __builtin_nontemporal_load(et2u + i - 2 * NE_);
            b = m >> 11;
        } else {
            int m2 = (i < 5 * NE_) ? __builtin_nontemporal_load(eu2t + i - 4 * NE_)
                                   : (NU_ + __builtin_nontemporal_load(et2u + i - 5 * NE_));
            b = NBKC + (m2 >> 11);
        }
        atomicAdd(&cnt[b], 1);
    }
    __syncthreads();
    for (int j = threadIdx.x; j < NBKT; j += 256) {
        bofs[bid * NBKT + j] = atomicAdd(&gcnt[j], cnt[j]);
    }
}

// fused: weight-convert (blocks 0..CVB) + p1 (blocks CVB..CVB+PB1), independent work
__global__ __launch_bounds__(256) void fused_cvt_p1(
    Ptr10 src, float* __restrict__ wts, const int* __restrict__ flag,
    const int* __restrict__ eu2u, const int* __restrict__ et2t,
    const int* __restrict__ eu2t, const int* __restrict__ et2u,
    int* __restrict__ gcnt, int* __restrict__ bofs) {
    int b = blockIdx.x;
    if (b < CVB) {
        cvt_dev(b * 256 + threadIdx.x, src, wts, flag);
    } else {
        p1_dev(b - CVB, eu2u, et2t, eu2t, et2u, gcnt, bofs);
    }
}

// ---------------- partition pass 2 (device body) ----------------
__device__ __forceinline__ void p2_dev(int bid, const int* __restrict__ eu2u,
                                       const int* __restrict__ et2t,
                                       const int* __restrict__ eu2t,
                                       const int* __restrict__ et2u,
                                       const int* __restrict__ gcnt, int* __restrict__ gbase,
                                       const int* __restrict__ bofs,
                                       unsigned int* __restrict__ part_csr,
                                       unsigned int* __restrict__ part_src) {
    __shared__ int gb[NBKT];
    __shared__ int lofs[NBKT];
    const int t = threadIdx.x;
    for (int j = t; j < NBKT; j += 256) { lofs[j] = 0; gb[j] = gcnt[j]; }
    __syncthreads();
    if (t == 0) {
        int s = 0;
        for (int j = 0; j < NBKC; ++j) { int c = gb[j]; gb[j] = s; s += c; }
        s = 0;
        for (int j = NBKC; j < NBKT; ++j) { int c = gb[j]; gb[j] = s; s += c; }
    }
    __syncthreads();
    if (bid == 0)
        for (int j = t; j < NBKT; j += 256) gbase[j] = gb[j];
    for (int i = bid * 256 + t; i < 6 * NE_; i += PB1 * 256) {
        if (i < 4 * NE_) {
            int m; unsigned int src, tag;
            if (i < NE_)          { m = __builtin_nontemporal_load(eu2u + i + NE_);
                                    src = (unsigned int)__builtin_nontemporal_load(eu2u + i);            tag = 0u; }
            else if (i < 2 * NE_) { m = NU_ + __builtin_nontemporal_load(et2t + i);
                                    src = (unsigned int)__builtin_nontemporal_load(et2t + i - NE_);      tag = 0u; }
            else if (i < 3 * NE_) { m = NU_ + __builtin_nontemporal_load(eu2t + i - NE_);
                                    src = (unsigned int)__builtin_nontemporal_load(eu2t + i - 2 * NE_);  tag = 1u; }
            else                  { m = __builtin_nontemporal_load(et2u + i - 2 * NE_);
                                    src = (unsigned int)__builtin_nontemporal_load(et2u + i - 3 * NE_);  tag = 1u; }
            int b = m >> 11;
            int l = atomicAdd(&lofs[b], 1);
            int pos = gb[b] + bofs[bid * NBKT + b] + l;
            part_csr[pos] = (src << 12) | (tag << 11) | (unsigned int)(m & (BKP - 1));
        } else {
            int m2 = (i < 5 * NE_) ? __builtin_nontemporal_load(eu2t + i - 4 * NE_)
                                   : (NU_ + __builtin_nontemporal_load(et2u + i - 5 * NE_));
            int b = NBKC + (m2 >> 11);
            int l = atomicAdd(&lofs[b], 1);
            int pos = gb[b] + bofs[bid * NBKT + b] + l;
            part_src[pos] = (unsigned int)m2;
        }
    }
}

// fused: pack/compose (blocks 0..PKB) + p2 scatter (blocks PKB..PKB+PB1)
__global__ __launch_bounds__(256) void fused_pack_p2(
    const float* __restrict__ wts, _Float16* __restrict__ wpk, float* __restrict__ bcomp,
    const int* __restrict__ eu2u, const int* __restrict__ et2t,
    const int* __restrict__ eu2t, const int* __restrict__ et2u,
    const int* __restrict__ gcnt, int* __restrict__ gbase, const int* __restrict__ bofs,
    unsigned int* __restrict__ part_csr, unsigned int* __restrict__ part_src) {
    int b = blockIdx.x;
    if (b < PKB) {
        pack_dev(b * 256 + threadIdx.x, wts, wpk, bcomp);
    } else {
        p2_dev(b - PKB, eu2u, et2t, eu2t, et2u, gcnt, gbase, bofs, part_csr, part_src);
    }
}

// ---------------- bucket_build: count + scan + meta/dinv + place (single pass) ----------------
__global__ __launch_bounds__(1024) void bucket_build(
    const unsigned int* __restrict__ part_csr, const unsigned int* __restrict__ part_src,
    const int* __restrict__ gcnt, const int* __restrict__ gbase,
    float* __restrict__ dinv, int4* __restrict__ meta,
    int* __restrict__ colU, int* __restrict__ colT) {
    const int b = blockIdx.x;
    const int t = threadIdx.x;
    if (b >= NBKC) {
        __shared__ int cS[BKP];
        const int n = gcnt[b];
        const int base = gbase[b];
        for (int j = t; j < BKP; j += 1024) cS[j] = 0;
        __syncthreads();
        for (int i = t; i < n; i += 1024)
            atomicAdd(&cS[(int)(__builtin_nontemporal_load(part_src + base + i) & (BKP - 1))], 1);
        __syncthreads();
        const int m0 = (b - NBKC) << 11;
        for (int j = t; j < BKP; j += 1024) {
            int m2 = m0 + j;
            if (m2 < NU_ + NT_) {
                int o = (m2 < NU_) ? (OFF4 + m2) : (OFF5 + (m2 - NU_));
                int h = cS[j];
                dinv[o] = (h > 0) ? rsqrtf((float)h) : 0.f;
            }
        }
        return;
    }
    __shared__ int cA[BKP];
    __shared__ int cB[BKP];
    __shared__ int lp[BKP];
    __shared__ int s1[1024];
    const int n = gcnt[b];
    const int base = gbase[b];
    for (int j = t; j < BKP; j += 1024) { cA[j] = 0; cB[j] = 0; }
    __syncthreads();
    for (int i = t; i < n; i += 1024) {
        unsigned int it = __builtin_nontemporal_load(part_csr + base + i);
        int l = (int)(it & (BKP - 1));
        if (it & 0x800u) atomicAdd(&cB[l], 1);
        else             atomicAdd(&cA[l], 1);
    }
    __syncthreads();
    const int j0 = t << 1, j1 = j0 + 1;
    const int a0 = cA[j0] + cB[j0];
    const int a1 = cA[j1] + cB[j1];
    const int ps = a0 + a1;
    s1[t] = ps;
    __syncthreads();
    for (int off = 1; off < 1024; off <<= 1) {
        int x = (t >= off) ? s1[t - off] : 0;
        __syncthreads();
        s1[t] += x;
        __syncthreads();
    }
    const int excl = s1[t] - ps;
    lp[j0] = excl;
    lp[j1] = excl + a0;
    __syncthreads();
    const int m0 = b << 11;
    const int gb0 = gbase[b];
    for (int j = t; j < BKP; j += 1024) {
        int m = m0 + j;
        if (m < NU_ + NT_) {
            int hA = cA[j], hB = cB[j];
            float dslf = rsqrtf((float)hA + 1.0f);
            int oA = (m < NU_) ? (OFF0 + m) : (OFF1 + (m - NU_));
            dinv[oA] = dslf;
            int4 mt;
            mt.x = gb0 + lp[j] - ((m >= NU_) ? 2 * NE_ : 0);
            mt.y = hA + hB;
            mt.z = __float_as_int(0.5f * dslf);
            mt.w = __float_as_int((hB > 0) ? 0.5f * rsqrtf((float)hB) : 0.f);
            meta[m] = mt;
        }
    }
    __syncthreads();
    for (int j = t; j < BKP; j += 1024) cA[j] = 0;
    __syncthreads();
    for (int i = t; i < n; i += 1024) {
        unsigned int it = __builtin_nontemporal_load(part_csr + base + i);
        int mlow = (int)(it & (BKP - 1));
        int ofs = atomicAdd(&cA[mlow], 1);
        int g = gb0 + lp[mlow] + ofs;
        int colv = (int)(((it >> 12) << 6) | ((it & 0x800u) << 20));
        int m = m0 + mlow;
        if (m < NU_) colU[g] = colv;
        else         colT[g - 2 * NE_] = colv;
    }
}

// ---------------- layer-0 GEMM: msg = (X @ W' + b') * sc  (embed folded in) ----------------
template <int K>
__device__ __forceinline__ void gemm0_dev(int t0, int tstride, int ntiles,
                                          const void* __restrict__ x,
                                          const _Float16* __restrict__ WApk,
                                          const _Float16* __restrict__ WBpk,
                                          const float* __restrict__ bA,
                                          const float* __restrict__ bB,
                                          const float* __restrict__ scA,
                                          const float* __restrict__ scB,
                                          unsigned char* __restrict__ mA,
                                          unsigned char* __restrict__ mB,
                                          const int* __restrict__ flag) {
    constexpr int KS = K / 32;
    const int lane = threadIdx.x & 63;
    const int rq = lane & 15;
    const int oct = lane >> 4;

    f16x8 bf[2][4][KS];
#pragma unroll
    for (int m = 0; m < 2; ++m) {
        const _Float16* P = m ? WBpk : WApk;
#pragma unroll
        for (int ct = 0; ct < 4; ++ct)
#pragma unroll
            for (int s = 0; s < KS; ++s)
                bf[m][ct][s] = *(const f16x8*)(P + (((ct * KS + s) << 9) + (lane << 3)));
    }
    float bvA[4], bvB[4];
#pragma unroll
    for (int ct = 0; ct < 4; ++ct) { bvA[ct] = bA[16 * ct + rq]; bvB[ct] = bB[16 * ct + rq]; }

    const bool isb = flag[0] != 0;

    for (int t = t0; t < ntiles; t += tstride) {
        const int r0 = t << 4;
        f16x8 a[KS];
        if (isb) {
            const unsigned short* xr = (const unsigned short*)x + (size_t)(r0 + rq) * K + 8 * oct;
#pragma unroll
            for (int s = 0; s < KS; ++s) {
                u16x8 uv = *(const u16x8*)(xr + 32 * s);
                f16x8 v;
#pragma unroll
                for (int j = 0; j < 8; ++j)
                    v[j] = (_Float16)__uint_as_float(((unsigned int)uv[j]) << 16);
                a[s] = v;
            }
        } else {
            const float* xr = (const float*)x + (size_t)(r0 + rq) * K + 8 * oct;
#pragma unroll
            for (int s = 0; s < KS; ++s) {
                float4 x0 = *(const float4*)(xr + 32 * s);
                float4 x1 = *(const float4*)(xr + 32 * s + 4);
                f16x8 v;
                v[0] = (_Float16)x0.x; v[1] = (_Float16)x0.y;
                v[2] = (_Float16)x0.z; v[3] = (_Float16)x0.w;
                v[4] = (_Float16)x1.x; v[5] = (_Float16)x1.y;
                v[6] = (_Float16)x1.z; v[7] = (_Float16)x1.w;
                a[s] = v;
            }
        }

        f32x4 acc[2][4];
#pragma unroll
        for (int m = 0; m < 2; ++m)
#pragma unroll
            for (int ct = 0; ct < 4; ++ct) acc[m][ct] = (f32x4){0.f, 0.f, 0.f, 0.f};
#pragma unroll
        for (int m = 0; m < 2; ++m)
#pragma unroll
            for (int ct = 0; ct < 4; ++ct)
#pragma unroll
                for (int s = 0; s < KS; ++s)
                    acc[m][ct] = __builtin_amdgcn_mfma_f32_16x16x32_f16(a[s], bf[m][ct][s],
                                                                       acc[m][ct], 0, 0, 0);

        const int rb = r0 + (oct << 2);
        float sa[4], sb[4];
#pragma unroll
        for (int g = 0; g < 4; ++g) { sa[g] = scA[rb + g]; sb[g] = scB[rb + g]; }
#pragma unroll
        for (int ct = 0; ct < 4; ++ct)
#pragma unroll
            for (int g = 0; g < 4; ++g) {
                mA[(size_t)(rb + g) * HD + 16 * ct + rq] =
                    enc_fp8((acc[0][ct][g] + bvA[ct]) * sa[g]);
                mB[(size_t)(rb + g) * HD + 16 * ct + rq] =
                    enc_fp8((acc[1][ct][g] + bvB[ct]) * sb[g]);
            }
    }
}

__global__ __launch_bounds__(256) void gemm0_both(
    const void* __restrict__ x_user, const void* __restrict__ x_txn,
    const _Float16* __restrict__ wpk, const float* __restrict__ bcomp,
    const float* __restrict__ dinv,
    unsigned char* __restrict__ m_uu, unsigned char* __restrict__ m_ut,
    unsigned char* __restrict__ m_tt, unsigned char* __restrict__ m_tu,
    const int* __restrict__ flag) {
    int b = blockIdx.x;
    int wid = threadIdx.x >> 6;
    if (b < GMU) {
        gemm0_dev<32>(b * 4 + wid, GMU * 4, NU_ / 16, x_user,
                      wpk + WPK_G0U, wpk + WPK_G0U + 2048,
                      bcomp + 0, bcomp + 128,
                      dinv + OFF0, dinv + OFF4, m_uu, m_ut, flag);
    } else {
        gemm0_dev<64>((b - GMU) * 4 + wid, GMT * 4, NT_ / 16, x_txn,
                      wpk + WPK_G0T, wpk + WPK_G0T + 4096,
                      bcomp + 64, bcomp + 192,
                      dinv + OFF1, dinv + OFF5, m_tt, m_tu, flag);
    }
}

// ---------------- gather edge-accumulation phase ----------------
__device__ __forceinline__ void gather_phase(int d, bool valid,
                                             const unsigned char* __restrict__ msg,
                                             unsigned int offB,
                                             const int4* __restrict__ meta,
                                             const int* __restrict__ col,
                                             const float* __restrict__ ba,
                                             const float* __restrict__ bb,
                                             float* __restrict__ af) {
    const int lane = threadIdx.x & 63;
    const int grp = lane >> 3;
    const int sub = lane & 7;

    i32x4 mt = (i32x4){0, 0, 0, 0};
    if (valid) mt = __builtin_nontemporal_load((const i32x4*)(meta + d));
    const int st = mt.x;
    const int cnt = mt.y;
    const float dA = __int_as_float(mt.z);
    const float dB = __int_as_float(mt.w);
    const unsigned char* msgL = msg + (sub << 3);

    floatx2 acc[4];
#pragma unroll
    for (int q = 0; q < 4; ++q) acc[q] = (floatx2){0.f, 0.f};

    auto consume = [&](uint2 u, float s) {
        floatx2 s2; s2.x = s; s2.y = s;
#if __has_builtin(__builtin_amdgcn_cvt_pk_f32_fp8)
        acc[0] += __builtin_amdgcn_cvt_pk_f32_fp8((int)u.x, false) * s2;
        acc[1] += __builtin_amdgcn_cvt_pk_f32_fp8((int)u.x, true) * s2;
        acc[2] += __builtin_amdgcn_cvt_pk_f32_fp8((int)u.y, false) * s2;
        acc[3] += __builtin_amdgcn_cvt_pk_f32_fp8((int)u.y, true) * s2;
#else
        float f[8];
        dec4_fp8(u.x, f);
        dec4_fp8(u.y, f + 4);
        acc[0].x += f[0] * s; acc[0].y += f[1] * s;
        acc[1].x += f[2] * s; acc[1].y += f[3] * s;
        acc[2].x += f[4] * s; acc[2].y += f[5] * s;
        acc[3].x += f[6] * s; acc[3].y += f[7] * s;
#endif
    };

    if (valid) {
        uint2 uself = *(const uint2*)(msgL + ((unsigned int)d << 6));
        consume(uself, dA);
    }

    int cw = (sub < cnt) ? __builtin_nontemporal_load(col + st + sub) : 0;
    int done = 0;
    while (done < cnt) {
        int rem = cnt - done;
        if (rem > 8) rem = 8;

        uint2 ub0, ub1, ub2, ub3, ub4, ub5, ub6, ub7;
        float sc0, sc1, sc2, sc3, sc4, sc5, sc6, sc7;

        auto issue = [&](int p, uint2& ub, float& sc) {
            int c = __shfl(cw, (grp << 3) + p);
            unsigned int off = ((unsigned int)c & 0x7fffffffu) + ((c < 0) ? offB : 0u);
            sc = (p < rem) ? ((c < 0) ? dB : dA) : 0.f;
            ub = *(const uint2*)(msgL + off);
        };

        issue(0, ub0, sc0);
        issue(1, ub1, sc1);
        issue(2, ub2, sc2);
        issue(3, ub3, sc3);
        issue(4, ub4, sc4);
        issue(5, ub5, sc5);
        issue(6, ub6, sc6);
        issue(7, ub7, sc7);

        int nd = done + 8;
        int cw2 = (nd + sub < cnt) ? __builtin_nontemporal_load(col + st + nd + sub) : 0;

        consume(ub0, sc0);
        consume(ub1, sc1);
        consume(ub2, sc2);
        consume(ub3, sc3);
        consume(ub4, sc4);
        consume(ub5, sc5);
        consume(ub6, sc6);
        consume(ub7, sc7);

        cw = cw2;
        done = nd;
    }

    const int col0 = sub << 3;
    float4 a0 = *(const float4*)(ba + col0);
    float4 a1 = *(const float4*)(ba + col0 + 4);
    float4 c0 = *(const float4*)(bb + col0);
    float4 c1 = *(const float4*)(bb + col0 + 4);
    float av[8] = {acc[0].x, acc[0].y, acc[1].x, acc[1].y,
                   acc[2].x, acc[2].y, acc[3].x, acc[3].y};
    float bv[8] = {a0.x + c0.x, a0.y + c0.y, a0.z + c0.z, a0.w + c0.w,
                   a1.x + c1.x, a1.y + c1.y, a1.z + c1.z, a1.w + c1.w};
#pragma unroll
    for (int k = 0; k < 8; ++k)
        af[k] = fmaxf(av[k] + 0.5f * bv[k], 0.f);
}

// ---------------- final gather + in-block column reduce -> partials ----------------
__global__ __launch_bounds__(256) void gather_red_both(
    const unsigned char* __restrict__ msgU, const unsigned char* __restrict__ msgT,
    const int4* __restrict__ meta,
    const int* __restrict__ colU, const int* __restrict__ colT,
    const float* __restrict__ bU0, const float* __restrict__ bU1,
    const float* __restrict__ bT0, const float* __restrict__ bT1,
    float* __restrict__ partU, float* __restrict__ partT) {
    __shared__ float hs[32][64];
    __shared__ float ps[4][64];
    int b = blockIdx.x;
    const bool isU = b < GBU;
    const int blk = isU ? b : b - GBU;
    const int grp = (threadIdx.x & 63) >> 3;
    const int sub = threadIdx.x & 7;
    const int w = threadIdx.x >> 6;
    const int d = (blk << 5) + (w << 3) + grp;
    const int N = isU ? NU_ : NT_;
    float af[8];
    gather_phase(d, d < N,
                 isU ? msgU : msgT, (unsigned int)(isU ? NU_ : NT_) * HD,
                 isU ? meta : meta + NU_, isU ? colU : colT,
                 isU ? bU0 : bT0, isU ? bU1 : bT1, af);
    {
        const int ld = threadIdx.x >> 3;
#pragma unroll
        for (int k = 0; k < 8; ++k) hs[ld][(sub << 3) + k] = (d < N) ? af[k] : 0.f;
    }
    __syncthreads();
    const int c = threadIdx.x & 63;
    const int r0 = w << 3;
    float s = 0.f;
#pragma unroll
    for (int r = 0; r < 8; ++r) s += hs[r0 + r][c];
    ps[w][c] = s;
    __syncthreads();
    if (threadIdx.x < 64) {
        float t = ps[0][c] + ps[1][c] + ps[2][c] + ps[3][c];
        (isU ? partU : partT)[(size_t)blk * 64 + c] = t;
    }
}

// ---------------- fused gather + next-layer dual GEMM (4-wave MFMA split) ----------------
__global__ __launch_bounds__(256) void gather_gemm_both(
    const unsigned char* __restrict__ msgU, const unsigned char* __restrict__ msgT,
    const int4* __restrict__ meta,
    const int* __restrict__ colU, const int* __restrict__ colT,
    const float* __restrict__ bU0, const float* __restrict__ bU1,
    const float* __restrict__ bT0, const float* __restrict__ bT1,
    const _Float16* __restrict__ WUa, const _Float16* __restrict__ WUb,
    const _Float16* __restrict__ WTa, const _Float16* __restrict__ WTb,
    const float* __restrict__ dinv,
    unsigned char* __restrict__ o_uu, unsigned char* __restrict__ o_ut,
    unsigned char* __restrict__ o_tt, unsigned char* __restrict__ o_tu) {
    __shared__ _Float16 hs[32][64];
    int b = blockIdx.x;
    const bool isU = b < GBU;
    const int blk = isU ? b : b - GBU;
    const int lane = threadIdx.x & 63;
    const int grp = lane >> 3;
    const int sub = lane & 7;
    const int w = threadIdx.x >> 6;
    const int d = (blk << 5) + (w << 3) + grp;
    const int N = isU ? NU_ : NT_;

    float af[8];
    gather_phase(d, d < N,
                 isU ? msgU : msgT, (unsigned int)(isU ? NU_ : NT_) * HD,
                 isU ? meta : meta + NU_, isU ? colU : colT,
                 isU ? bU0 : bT0, isU ? bU1 : bT1, af);

    {
        const int ld = threadIdx.x >> 3;
        f16x8 o;
#pragma unroll
        for (int k = 0; k < 8; ++k) o[k] = (_Float16)af[k];
        *(f16x8*)(&hs[ld][sub << 3]) = o;
    }
    __syncthreads();

    // wave w: row-half = w&1, matrix = w>>1 (8 MFMAs each, no idle waves)
    {
        const int half = w & 1;
        const int mi = w >> 1;
        const _Float16* P = mi ? (isU ? WUb : WTb) : (isU ? WUa : WTa);
        unsigned char* mOut = mi ? (isU ? o_ut : o_tu) : (isU ? o_uu : o_tt);
        const float* sc = dinv + (mi ? (isU ? OFF4 : OFF5) : (isU ? OFF0 : OFF1));
        const int rq = lane & 15;
        const int oct = lane >> 4;

        f16x8 bf[4][2];
#pragma unroll
        for (int ct = 0; ct < 4; ++ct)
#pragma unroll
            for (int s = 0; s < 2; ++s)
                bf[ct][s] = *(const f16x8*)(P + ((((ct << 1) + s) << 9) + (lane << 3)));

        f16x8 a0 = *(const f16x8*)(&hs[16 * half + rq][8 * oct]);
        f16x8 a1 = *(const f16x8*)(&hs[16 * half + rq][32 + 8 * oct]);

        f32x4 acc[4];
#pragma unroll
        for (int ct = 0; ct < 4; ++ct) acc[ct] = (f32x4){0.f, 0.f, 0.f, 0.f};
#pragma unroll
        for (int ct = 0; ct < 4; ++ct) {
            acc[ct] = __builtin_amdgcn_mfma_f32_16x16x32_f16(a0, bf[ct][0], acc[ct], 0, 0, 0);
            acc[ct] = __builtin_amdgcn_mfma_f32_16x16x32_f16(a1, bf[ct][1], acc[ct], 0, 0, 0);
        }

        const int rb = (blk << 5) + 16 * half + (oct << 2);
        float sv[4];
#pragma unroll
        for (int g = 0; g < 4; ++g) sv[g] = sc[rb + g];
#pragma unroll
        for (int ct = 0; ct < 4; ++ct)
#pragma unroll
            for (int g = 0; g < 4; ++g)
                mOut[(size_t)(rb + g) * HD + 16 * ct + rq] = enc_fp8(acc[ct][g] * sv[g]);
    }
}

// ---------------- readout: reduce partials; last block runs the MLP head ----------------
__global__ __launch_bounds__(256) void colmean_head(
    const float* __restrict__ partU, const float* __restrict__ partT,
    float* __restrict__ gsum, int* __restrict__ done,
    const float* __restrict__ W1, const float* __restrict__ b1,
    const float* __restrict__ W2, const float* __restrict__ b2,
    const int* __restrict__ flag, void* __restrict__ out) {
    const bool isU = blockIdx.x < 8;
    const float* p = isU ? partU : partT;
    const int rows = isU ? GBU : GBT;
    const float scale = isU ? 0.5f / NU_ : 0.5f / NT_;
    const int blk = isU ? blockIdx.x : blockIdx.x - 8;
    const int lane = threadIdx.x & 63;
    const int wv = threadIdx.x >> 6;
    float s = 0.f;
    for (int r = blk * 4 + wv; r < rows; r += 32)
        s += p[(size_t)r * 64 + lane];
    __shared__ float red[256];
    __shared__ int islast;
    __shared__ float gsh[64];
    red[threadIdx.x] = s;
    __syncthreads();
    if (threadIdx.x < 64) {
        float t = red[threadIdx.x] + red[64 + threadIdx.x] + red[128 + threadIdx.x] +
                  red[192 + threadIdx.x];
        atomicAdd(&gsum[lane], t * scale);
    }
    __syncthreads();
    if (threadIdx.x == 0) {
        __threadfence();
        int prev = __hip_atomic_fetch_add(done, 1, __ATOMIC_ACQ_REL, __HIP_MEMORY_SCOPE_AGENT);
        islast = (prev == 15) ? 1 : 0;
    }
    __syncthreads();
    if (islast) {
        if (threadIdx.x < 64)
            gsh[threadIdx.x] = __hip_atomic_load(&gsum[threadIdx.x], __ATOMIC_RELAXED,
                                                 __HIP_MEMORY_SCOPE_AGENT);
    }
    __syncthreads();
    if (islast && threadIdx.x < 64) {
        const int c = threadIdx.x;
        float x = b1[c];
        for (int k = 0; k < HD; ++k) x = fmaf(gsh[k], W1[k * HD + c], x);
        x = fmaxf(x, 0.f);
        float t = x * W2[c];
        for (int off = 32; off; off >>= 1) t += __shfl_down(t, off);
        if (c == 0) {
            float z = t + b2[0];
            float sg = 1.f / (1.f + expf(-z));
            if (flag[0]) *(__hip_bfloat16*)out = __float2bfloat16(sg);
            else *(float*)out = sg;
        }
    }
}

extern "C" void kernel_launch(void* const* d_in, const int* in_sizes, int n_in,
                              void* d_out, int out_size, void* d_ws, size_t ws_size,
                              hipStream_t stream) {
    const void* x_user = d_in[0];
    const void* x_txn  = d_in[1];
    const int* ei_u2u = (const int*)d_in[2];
    const int* ei_t2t = (const int*)d_in[3];
    const int* ei_u2t = (const int*)d_in[4];
    const int* ei_t2u = (const int*)d_in[5];

    // ---- workspace layout ----
    float* ws = (float*)d_ws;
    float* partU = ws;                                // GBU*64 f32
    float* partT = partU + (size_t)GBU * 64;          // GBT*64 f32
    float* dinv = (float*)((_Float16*)ws + (size_t)RPT2 * HD);  // HTOT f32
    float* wts = dinv + HTOT;                         // 60432
    float* gsum = wts + 60432;                        // 64
    float* bcomp = gsum + 64;                         // 256
    _Float16* wpk = (_Float16*)(bcomp + 256);         // WPK_TOT f16
    unsigned char* msg0 = (unsigned char*)(wpk + WPK_TOT);  // set0: 600k rows fp8
    unsigned char* msg1 = msg0 + (size_t)(2 * NU_ + 2 * NT_) * HD;  // set1
    int* aux  = (int*)(msg1 + (size_t)(2 * NU_ + 2 * NT_) * HD);    // gcnt/gbase/bofs
    int* colU = aux + 2 * NBKT + PB1 * NBKT;          // 2M
    int* colT = colU + 2 * NE_;                       // 2M
    int4* meta = (int4*)(colT + 2 * NE_);             // RPT2
    int* dflag = (int*)(meta + RPT2);                 // 1
    int* done  = dflag + 1;                           // 1

    int* gcnt  = aux;               // NBKT
    int* gbase = gcnt + NBKT;       // NBKT
    int* bofs  = gbase + NBKT;      // PB1*NBKT

    // msg sub-tables per set: m_uu | m_tu | m_tt | m_ut
    auto uu = [](unsigned char* s) { return s; };
    auto tu = [](unsigned char* s) { return s + (size_t)NU_ * HD; };
    auto tt = [](unsigned char* s) { return s + (size_t)(NU_ + NT_) * HD; };
    auto ut = [](unsigned char* s) { return s + (size_t)(NU_ + 2 * NT_) * HD; };

    // partition payload aliases (consumed by bucket_build before first writes)
    unsigned int* part_csr = (unsigned int*)msg1;     // 16 MB over set1
    unsigned int* part_src = (unsigned int*)ws;       // 8 MB over partials region

    // fp32 weight sub-pointers
    float* W1f = wts + 56192;
    float* b1f = W1f + 4096;
    float* W2f = b1f + 64;
    float* b2f = W2f + 64;
    const float* convbf = wts + 55424;

    // 1. detect dtype + zero gsum/gcnt/done
    detect_dtype<<<1, 256, 0, stream>>>((const unsigned short*)x_user, dflag,
                                        gsum, gcnt, done, 2048);

    // 2. weight convert (tiny) overlapped with partition pass 1 (memory-heavy)
    {
        Ptr10 p;
        for (int k = 0; k < 10; ++k) p.p[k] = d_in[6 + k];
        fused_cvt_p1<<<CVB + PB1, 256, 0, stream>>>(p, wts, dflag,
                                                    ei_u2u, ei_t2t, ei_u2t, ei_t2u,
                                                    gcnt, bofs);
    }

    // 3. weight pack/compose (compute) overlapped with partition scatter (memory-heavy)
    fused_pack_p2<<<PKB + PB1, 256, 0, stream>>>(wts, wpk, bcomp,
                                                 ei_u2u, ei_t2t, ei_u2t, ei_t2u,
                                                 gcnt, gbase, bofs, part_csr, part_src);

    // 4. single-pass CSR build
    bucket_build<<<NBKT, 1024, 0, stream>>>(part_csr, part_src, gcnt, gbase,
                                            dinv, meta, colU, colT);

    // 5. layer 0 gemm (embed folded): x -> msg set0
    gemm0_both<<<GMU + GMT, 256, 0, stream>>>(x_user, x_txn, wpk, bcomp, dinv,
                                              uu(msg0), ut(msg0), tt(msg0), tu(msg0), dflag);

    // 6-7. fused gather(l) + gemm(l+1): set_in -> set_out (h never hits memory)
    for (int l = 0; l < 2; ++l) {
        unsigned char* in  = (l == 0) ? msg0 : msg1;
        unsigned char* out = (l == 0) ? msg1 : msg0;
        const float* B0   = convbf + ((size_t)l * 4 + 0) * HD;
        const float* Bt   = convbf + ((size_t)l * 4 + 1) * HD;
        const float* Bu2t = convbf + ((size_t)l * 4 + 2) * HD;
        const float* Bt2u = convbf + ((size_t)l * 4 + 3) * HD;
        const _Float16* W0n   = wpk + WPK_CONV + ((size_t)(l + 1) * 4 + 0) * 4096;
        const _Float16* Wtn   = wpk + WPK_CONV + ((size_t)(l + 1) * 4 + 1) * 4096;
        const _Float16* Wu2tn = wpk + WPK_CONV + ((size_t)(l + 1) * 4 + 2) * 4096;
        const _Float16* Wt2un = wpk + WPK_CONV + ((size_t)(l + 1) * 4 + 3) * 4096;

        gather_gemm_both<<<GBU + GBT, 256, 0, stream>>>(
            uu(in), tt(in), meta, colU, colT,
            B0, Bt2u, Bt, Bu2t,
            W0n, Wu2tn, Wtn, Wt2un, dinv,
            uu(out), ut(out), tt(out), tu(out));
    }

    // 8. final layer: gather + in-block column reduce -> partials
    {
        const float* B0   = convbf + (2 * 4 + 0) * HD;
        const float* Bt   = convbf + (2 * 4 + 1) * HD;
        const float* Bu2t = convbf + (2 * 4 + 2) * HD;
        const float* Bt2u = convbf + (2 * 4 + 3) * HD;
        gather_red_both<<<GBU + GBT, 256, 0, stream>>>(uu(msg0), tt(msg0),
                                                       meta, colU, colT,
                                                       B0, Bt2u, Bt, Bu2t, partU, partT);
    }

    // 9. readout: partial reduce + head (last block)
    colmean_head<<<16, 256, 0, stream>>>(partU, partT, gsum, done,
                                         W1f, b1f, W2f, b2f, dflag, d_out);
}